// Round 1
// baseline (134.059 us; speedup 1.0000x reference)
//
#include <hip/hip_runtime.h>

typedef __attribute__((ext_vector_type(8))) short short8;
typedef __attribute__((ext_vector_type(4))) float f32x4;

#define IN_DIM 256
#define OUT_DIM 256
#define NB 16                 // padded basis count (13 real + 3 zero)
#define KDIM (IN_DIM * NB)    // 4096
#define TM 128
#define TN 128
#define BK 64                 // 4 i-values per K-step
#define LDA 72                // padded LDS row stride (bf16 elems) -> 2-way max conflicts
#define STEPS 32              // 2048 K per block (split-K = 2)

__device__ __forceinline__ unsigned short f2bf(float f) {
  union { float f; unsigned int u; } v; v.f = f;
  unsigned int r = v.u + 0x7fffu + ((v.u >> 16) & 1u);  // RNE
  return (unsigned short)(r >> 16);
}

// --- prep: BmT[o][i*16+n] = bf16( sum_e softmax(gating[i,o,:])[e] * coeff[e,n] ), n>=13 -> 0
__global__ __launch_bounds__(256) void kan_prep(const float* __restrict__ coeff,
                                                const float* __restrict__ gw,
                                                unsigned short* __restrict__ BmT) {
  __shared__ float csh[104];
  const int t = threadIdx.x;
  if (t < 104) csh[t] = coeff[t];
  __syncthreads();
  const int o = blockIdx.x;   // 256 blocks
  const int i = t;            // 256 threads
  const float* g = gw + (size_t)(i * OUT_DIM + o) * 8;
  float4 g0 = *(const float4*)g;
  float4 g1 = *(const float4*)(g + 4);
  float ge[8] = {g0.x, g0.y, g0.z, g0.w, g1.x, g1.y, g1.z, g1.w};
  float mx = ge[0];
#pragma unroll
  for (int e = 1; e < 8; ++e) mx = fmaxf(mx, ge[e]);
  float p[8]; float s = 0.f;
#pragma unroll
  for (int e = 0; e < 8; ++e) { p[e] = __expf(ge[e] - mx); s += p[e]; }
  const float inv = 1.0f / s;
  unsigned short row[16];
#pragma unroll
  for (int n = 0; n < 13; ++n) {
    float w = 0.f;
#pragma unroll
    for (int e = 0; e < 8; ++e) w += p[e] * csh[e * 13 + n];
    row[n] = f2bf(w * inv);
  }
  row[13] = 0; row[14] = 0; row[15] = 0;
  int4* dst = (int4*)(BmT + (size_t)o * KDIM + i * NB);
  dst[0] = *(const int4*)&row[0];
  dst[1] = *(const int4*)&row[8];
}

// --- fused basis + GEMM: out[m][o] += A[m][k] * BmT[o][k], k = i*16+n
__global__ __launch_bounds__(256) void kan_gemm(const float* __restrict__ x,
                                                const unsigned short* __restrict__ BmT,
                                                float* __restrict__ out) {
  __shared__ int4 AshR[(TM * LDA * 2) / 16];   // 18 KB
  __shared__ int4 BshR[(TN * LDA * 2) / 16];   // 18 KB
  unsigned short* Ash = (unsigned short*)AshR;
  unsigned short* Bsh = (unsigned short*)BshR;

  const int t = threadIdx.x;
  const int lane = t & 63;
  const int wave = t >> 6;
  const int wm = wave & 1, wn = wave >> 1;       // 2x2 waves, 64x64 each
  const int mb = blockIdx.x * TM;
  const int ob = blockIdx.y * TN;
  const int i0 = blockIdx.z * 128;               // split-K half

  // one-time zero of A tile (sparse-update invariant needs clean slate)
  {
    int4 z4; z4.x = z4.y = z4.z = z4.w = 0;
    for (int idx = t; idx < (TM * LDA * 2) / 16; idx += 256) AshR[idx] = z4;
  }

  const int mloc = t & 127;
  const int il0 = t >> 7;                        // this thread covers il0 and il0+2
  const float* xp0 = x + (size_t)(mb + mloc) * IN_DIM + i0;
  const int arow = mloc * LDA;

  const unsigned short* bsrc[4];
  int bdst[4];
#pragma unroll
  for (int r = 0; r < 4; ++r) {
    int olo = (t >> 3) + 32 * r;
    bsrc[r] = BmT + (size_t)(ob + olo) * KDIM + i0 * NB + (t & 7) * 8;
    bdst[r] = olo * LDA + (t & 7) * 8;
  }

  f32x4 acc[4][4];
#pragma unroll
  for (int a = 0; a < 4; ++a)
#pragma unroll
    for (int b = 0; b < 4; ++b) acc[a][b] = (f32x4){0.f, 0.f, 0.f, 0.f};

  int aoff[4], boff[4];
#pragma unroll
  for (int f = 0; f < 4; ++f) {
    aoff[f] = (wm * 64 + f * 16 + (lane & 15)) * LDA + (lane >> 4) * 8;
    boff[f] = (wn * 64 + f * 16 + (lane & 15)) * LDA + (lane >> 4) * 8;
  }

  // software pipeline: preload step 0
  int4 breg[4];
  float xv[2];
#pragma unroll
  for (int r = 0; r < 4; ++r) breg[r] = *(const int4*)(bsrc[r]);
  xv[0] = xp0[il0];
  xv[1] = xp0[il0 + 2];
  int cprev[2] = {0, 0};

  for (int s = 0; s < STEPS; ++s) {
    __syncthreads();
    // stage B (preloaded regs -> LDS)
#pragma unroll
    for (int r = 0; r < 4; ++r) *(int4*)&Bsh[bdst[r]] = breg[r];
    // stage A: two spline evals, sparse 4-slot update
#pragma unroll
    for (int r = 0; r < 2; ++r) {
      const int il = il0 + 2 * r;
      float xc = fminf(fmaxf(xv[r], -1.0f), 1.0f - 1e-6f);
      float u = (xc + 1.0f) * 5.0f;              // h = 0.2
      int c = (int)u;
      c = c > 9 ? 9 : (c < 0 ? 0 : c);
      float tt = u - (float)c;
      float omt = 1.0f - tt;
      float t2 = tt * tt, t3 = t2 * tt;
      float b0 = omt * omt * omt * (1.0f / 6.0f);
      float b1 = (3.0f * t3 - 6.0f * t2 + 4.0f) * (1.0f / 6.0f);
      float b2 = (-3.0f * t3 + 3.0f * t2 + 3.0f * tt + 1.0f) * (1.0f / 6.0f);
      float b3 = t3 * (1.0f / 6.0f);
      unsigned short* rowp = Ash + arow + il * NB;
      const int cp = cprev[r];
      rowp[cp] = 0; rowp[cp + 1] = 0; rowp[cp + 2] = 0; rowp[cp + 3] = 0;
      rowp[c] = f2bf(b0); rowp[c + 1] = f2bf(b1);
      rowp[c + 2] = f2bf(b2); rowp[c + 3] = f2bf(b3);
      cprev[r] = c;
    }
    // prefetch next step's globals (lands during MFMA phase)
    if (s + 1 < STEPS) {
#pragma unroll
      for (int r = 0; r < 4; ++r) breg[r] = *(const int4*)(bsrc[r] + (s + 1) * BK);
      const float* xp = xp0 + (s + 1) * 4;
      xv[0] = xp[il0];
      xv[1] = xp[il0 + 2];
    }
    __syncthreads();
    // MFMA phase: 16 frag reads, 32 MFMAs per wave
#pragma unroll
    for (int kc = 0; kc < 2; ++kc) {
      short8 af[4], bfr[4];
#pragma unroll
      for (int f = 0; f < 4; ++f) af[f] = *(const short8*)&Ash[aoff[f] + kc * 32];
#pragma unroll
      for (int f = 0; f < 4; ++f) bfr[f] = *(const short8*)&Bsh[boff[f] + kc * 32];
#pragma unroll
      for (int mf = 0; mf < 4; ++mf)
#pragma unroll
        for (int nf = 0; nf < 4; ++nf)
          acc[mf][nf] = __builtin_amdgcn_mfma_f32_16x16x32_bf16(af[mf], bfr[nf], acc[mf][nf], 0, 0, 0);
    }
  }

  // epilogue: split-K accumulate
#pragma unroll
  for (int mf = 0; mf < 4; ++mf)
#pragma unroll
    for (int nf = 0; nf < 4; ++nf)
#pragma unroll
      for (int r = 0; r < 4; ++r) {
        int row = mb + wm * 64 + mf * 16 + ((lane >> 4) << 2) + r;
        int col = ob + wn * 64 + nf * 16 + (lane & 15);
        atomicAdd(out + (size_t)row * OUT_DIM + col, acc[mf][nf][r]);
      }
}

extern "C" void kernel_launch(void* const* d_in, const int* in_sizes, int n_in,
                              void* d_out, int out_size, void* d_ws, size_t ws_size,
                              hipStream_t stream) {
  const float* x     = (const float*)d_in[0];   // (4,2048,256) f32
  const float* coeff = (const float*)d_in[1];   // (8,13) f32
  const float* gw    = (const float*)d_in[2];   // (256,256,8) f32
  float* out = (float*)d_out;                   // (4,2048,256) f32
  unsigned short* BmT = (unsigned short*)d_ws;  // 256 x 4096 bf16 = 2 MB

  hipMemsetAsync(d_out, 0, (size_t)out_size * sizeof(float), stream);
  kan_prep<<<dim3(OUT_DIM), dim3(256), 0, stream>>>(coeff, gw, BmT);
  dim3 grid(8192 / TM, OUT_DIM / TN, 2);
  kan_gemm<<<grid, dim3(256), 0, stream>>>(x, BmT, out);
}

// Round 2
// 131.896 us; speedup vs baseline: 1.0164x; 1.0164x over previous
//
#include <hip/hip_runtime.h>

typedef __attribute__((ext_vector_type(8))) short short8;
typedef __attribute__((ext_vector_type(4))) float f32x4;

#define IN_DIM 256
#define OUT_DIM 256
#define NB 16                 // padded basis count (13 real + 3 zero)
#define KDIM (IN_DIM * NB)    // 4096
#define TM 128
#define TN 128
#define BK 64                 // 4 i-values per K-step
#define LDA 72                // padded LDS row stride (bf16 elems)
#define KSPLIT 4
#define IPER (IN_DIM / KSPLIT)   // 64 i-values per block
#define STEPS (IPER / 4)         // 16

__device__ __forceinline__ unsigned short f2bf(float f) {
  union { float f; unsigned int u; } v; v.f = f;
  unsigned int r = v.u + 0x7fffu + ((v.u >> 16) & 1u);  // RNE
  return (unsigned short)(r >> 16);
}

// --- prep: BmT[o][i*16+n] = bf16( sum_e softmax(gating[i,o,:])[e] * coeff[e,n] )
// grid (16,16): blockIdx.x = o-tile, blockIdx.y = i-tile; 256 threads = 16 i x 16 o.
__global__ __launch_bounds__(256) void kan_prep(const float* __restrict__ coeff,
                                                const float* __restrict__ gw,
                                                unsigned short* __restrict__ BmT) {
  __shared__ float csh[104];
  __shared__ unsigned short tile[16][256];   // [o_loc][il*16+n]  8 KB
  const int t = threadIdx.x;
  if (t < 104) csh[t] = coeff[t];
  __syncthreads();
  const int otile = blockIdx.x, itile = blockIdx.y;
  const int il = t >> 4, ol = t & 15;
  const int i = itile * 16 + il;
  const int o = otile * 16 + ol;
  // coalesced: 16 consecutive o -> 512B contiguous segment
  const float* g = gw + (size_t)(i * OUT_DIM + o) * 8;
  float4 g0 = *(const float4*)g;
  float4 g1 = *(const float4*)(g + 4);
  float ge[8] = {g0.x, g0.y, g0.z, g0.w, g1.x, g1.y, g1.z, g1.w};
  float mx = ge[0];
#pragma unroll
  for (int e = 1; e < 8; ++e) mx = fmaxf(mx, ge[e]);
  float p[8]; float s = 0.f;
#pragma unroll
  for (int e = 0; e < 8; ++e) { p[e] = __expf(ge[e] - mx); s += p[e]; }
  const float inv = 1.0f / s;
  unsigned short row[16];
#pragma unroll
  for (int n = 0; n < 13; ++n) {
    float w = 0.f;
#pragma unroll
    for (int e = 0; e < 8; ++e) w += p[e] * csh[e * 13 + n];
    row[n] = f2bf(w * inv);
  }
  row[13] = 0; row[14] = 0; row[15] = 0;
  int4* dst = (int4*)&tile[ol][il * 16];
  dst[0] = *(const int4*)&row[0];
  dst[1] = *(const int4*)&row[8];
  __syncthreads();
  // coalesced write-out: per o, a contiguous 512B run of BmT
  const int oo = t >> 4, ck = t & 15;       // 16 o x 16 chunks of 16B
  int4 v0 = *(const int4*)&tile[oo][ck * 16];
  int4 v1 = *(const int4*)&tile[oo][ck * 16 + 8];
  int4* out4 = (int4*)(BmT + (size_t)(otile * 16 + oo) * KDIM + itile * 256 + ck * 16);
  out4[0] = v0;
  out4[1] = v1;
}

// --- fused basis + GEMM: out[m][o] += A[m][k] * BmT[o][k], k = i*16+n
__global__ __launch_bounds__(256) void kan_gemm(const float* __restrict__ x,
                                                const unsigned short* __restrict__ BmT,
                                                float* __restrict__ out) {
  __shared__ int4 AshR[(TM * LDA * 2) / 16];   // 18 KB
  __shared__ int4 BshR[(TN * LDA * 2) / 16];   // 18 KB
  unsigned short* Ash = (unsigned short*)AshR;
  unsigned short* Bsh = (unsigned short*)BshR;

  const int t = threadIdx.x;
  const int lane = t & 63;
  const int wave = t >> 6;
  const int wm = wave & 1, wn = wave >> 1;       // 2x2 waves, 64x64 each
  const int mb = blockIdx.x * TM;
  const int ob = blockIdx.y * TN;
  const int i0 = blockIdx.z * IPER;              // split-K quarter

  // one-time zero of A tile (sparse-update invariant needs clean slate)
  {
    int4 z4; z4.x = z4.y = z4.z = z4.w = 0;
    for (int idx = t; idx < (TM * LDA * 2) / 16; idx += 256) AshR[idx] = z4;
  }

  const int mloc = t & 127;
  const int il0 = t >> 7;                        // this thread covers il0 and il0+2
  const float* xp0 = x + (size_t)(mb + mloc) * IN_DIM + i0;
  const int arow = mloc * LDA;

  const unsigned short* bsrc[4];
  int bdst[4];
#pragma unroll
  for (int r = 0; r < 4; ++r) {
    int olo = (t >> 3) + 32 * r;
    bsrc[r] = BmT + (size_t)(ob + olo) * KDIM + i0 * NB + (t & 7) * 8;
    bdst[r] = olo * LDA + (t & 7) * 8;
  }

  f32x4 acc[4][4];
#pragma unroll
  for (int a = 0; a < 4; ++a)
#pragma unroll
    for (int b = 0; b < 4; ++b) acc[a][b] = (f32x4){0.f, 0.f, 0.f, 0.f};

  int aoff[4], boff[4];
#pragma unroll
  for (int f = 0; f < 4; ++f) {
    aoff[f] = (wm * 64 + f * 16 + (lane & 15)) * LDA + (lane >> 4) * 8;
    boff[f] = (wn * 64 + f * 16 + (lane & 15)) * LDA + (lane >> 4) * 8;
  }

  // software pipeline: preload step 0
  int4 breg[4];
  float xv[2];
#pragma unroll
  for (int r = 0; r < 4; ++r) breg[r] = *(const int4*)(bsrc[r]);
  xv[0] = xp0[il0];
  xv[1] = xp0[il0 + 2];
  int cprev[2] = {0, 0};

  for (int s = 0; s < STEPS; ++s) {
    __syncthreads();
    // stage B (preloaded regs -> LDS)
#pragma unroll
    for (int r = 0; r < 4; ++r) *(int4*)&Bsh[bdst[r]] = breg[r];
    // stage A: two spline evals, sparse 4-slot update
#pragma unroll
    for (int r = 0; r < 2; ++r) {
      const int il = il0 + 2 * r;
      float xc = fminf(fmaxf(xv[r], -1.0f), 1.0f - 1e-6f);
      float u = (xc + 1.0f) * 5.0f;              // h = 0.2
      int c = (int)u;
      c = c > 9 ? 9 : (c < 0 ? 0 : c);
      float tt = u - (float)c;
      float omt = 1.0f - tt;
      float t2 = tt * tt, t3 = t2 * tt;
      float b0 = omt * omt * omt * (1.0f / 6.0f);
      float b1 = (3.0f * t3 - 6.0f * t2 + 4.0f) * (1.0f / 6.0f);
      float b2 = (-3.0f * t3 + 3.0f * t2 + 3.0f * tt + 1.0f) * (1.0f / 6.0f);
      float b3 = t3 * (1.0f / 6.0f);
      unsigned short* rowp = Ash + arow + il * NB;
      const int cp = cprev[r];
      rowp[cp] = 0; rowp[cp + 1] = 0; rowp[cp + 2] = 0; rowp[cp + 3] = 0;
      rowp[c] = f2bf(b0); rowp[c + 1] = f2bf(b1);
      rowp[c + 2] = f2bf(b2); rowp[c + 3] = f2bf(b3);
      cprev[r] = c;
    }
    // prefetch next step's globals (lands during MFMA phase)
    if (s + 1 < STEPS) {
#pragma unroll
      for (int r = 0; r < 4; ++r) breg[r] = *(const int4*)(bsrc[r] + (s + 1) * BK);
      const float* xp = xp0 + (s + 1) * 4;
      xv[0] = xp[il0];
      xv[1] = xp[il0 + 2];
    }
    __syncthreads();
    // MFMA phase: 16 frag reads, 32 MFMAs per wave
#pragma unroll
    for (int kc = 0; kc < 2; ++kc) {
      short8 af[4], bfr[4];
#pragma unroll
      for (int f = 0; f < 4; ++f) af[f] = *(const short8*)&Ash[aoff[f] + kc * 32];
#pragma unroll
      for (int f = 0; f < 4; ++f) bfr[f] = *(const short8*)&Bsh[boff[f] + kc * 32];
#pragma unroll
      for (int mf = 0; mf < 4; ++mf)
#pragma unroll
        for (int nf = 0; nf < 4; ++nf)
          acc[mf][nf] = __builtin_amdgcn_mfma_f32_16x16x32_bf16(af[mf], bfr[nf], acc[mf][nf], 0, 0, 0);
    }
  }

  // epilogue: split-K accumulate
#pragma unroll
  for (int mf = 0; mf < 4; ++mf)
#pragma unroll
    for (int nf = 0; nf < 4; ++nf)
#pragma unroll
      for (int r = 0; r < 4; ++r) {
        int row = mb + wm * 64 + mf * 16 + ((lane >> 4) << 2) + r;
        int col = ob + wn * 64 + nf * 16 + (lane & 15);
        atomicAdd(out + (size_t)row * OUT_DIM + col, acc[mf][nf][r]);
      }
}

extern "C" void kernel_launch(void* const* d_in, const int* in_sizes, int n_in,
                              void* d_out, int out_size, void* d_ws, size_t ws_size,
                              hipStream_t stream) {
  const float* x     = (const float*)d_in[0];   // (4,2048,256) f32
  const float* coeff = (const float*)d_in[1];   // (8,13) f32
  const float* gw    = (const float*)d_in[2];   // (256,256,8) f32
  float* out = (float*)d_out;                   // (4,2048,256) f32
  unsigned short* BmT = (unsigned short*)d_ws;  // 256 x 4096 bf16 = 2 MB

  hipMemsetAsync(d_out, 0, (size_t)out_size * sizeof(float), stream);
  kan_prep<<<dim3(16, 16), dim3(256), 0, stream>>>(coeff, gw, BmT);
  dim3 grid(8192 / TM, OUT_DIM / TN, KSPLIT);
  kan_gemm<<<grid, dim3(256), 0, stream>>>(x, BmT, out);
}